// Round 5
// baseline (145.248 us; speedup 1.0000x reference)
//
#include <hip/hip_runtime.h>
#include <hip/hip_cooperative_groups.h>

namespace cg = cooperative_groups;

#define NPTS   1024
#define HID    128
#define K_TAB  4096
#define U0f    (-10.0f)
#define U1f    (4.0f)
#define GPB    128          // blocks per batch (8 i's per block)

__device__ __forceinline__ float fast_exp2(float x) {
#if __has_builtin(__builtin_amdgcn_exp2f)
    return __builtin_amdgcn_exp2f(x);
#else
    return exp2f(x);
#endif
}
__device__ __forceinline__ float fast_rcp(float x) {
#if __has_builtin(__builtin_amdgcn_rcpf)
    return __builtin_amdgcn_rcpf(x);
#else
    return 1.0f / x;
#endif
}
__device__ __forceinline__ float fast_log2(float x) {
#if __has_builtin(__builtin_amdgcn_logf)
    return __builtin_amdgcn_logf(x);
#else
    return __log2f(x);
#endif
}
__device__ __forceinline__ float fast_rsq(float x) {
#if __has_builtin(__builtin_amdgcn_rsqf)
    return __builtin_amdgcn_rsqf(x);
#else
    return rsqrtf(x);
#endif
}
// tanh(x) = 1 - 2/(e^{2x}+1). Saturates correctly at +-inf.
__device__ __forceinline__ float fast_tanh(float x) {
    float e = fast_exp2(2.8853900817779268f * x);
    return 1.0f - 2.0f * fast_rcp(e + 1.0f);
}

// Single cooperative kernel.
// Phase 1: all 512 blocks together build the 4097-entry mag(d) table
//          (uniform in u = log2 d, d in [2^-10, 2^4]) into global tabg.
// grid.sync()
// Phase 2: each block stages the table + its batch's positions into LDS and
//          computes 8 output rows (i's); one wave handles 2 i's.
__global__ __launch_bounds__(256, 2)
void discovery_fused(const float* __restrict__ pos,
                     const float* __restrict__ W1,
                     const float* __restrict__ b1,
                     const float* __restrict__ W2,
                     const float* __restrict__ b2,
                     const float* __restrict__ W3,
                     const float* __restrict__ b3,
                     float* __restrict__ tabg,
                     float* __restrict__ out)
{
    // phase-2 layout: tab (K_TAB+4 floats) + pos (NPTS*3 floats) = 28.7 KB
    // phase-1 layout (overlaid): h1s[8][HID] (4 KB) + red[8][HID] (4 KB)
    __shared__ __align__(16) char smem[(K_TAB + 4) * 4 + NPTS * 3 * 4];
    float (*h1s)[HID] = (float (*)[HID])smem;
    float (*red)[HID] = (float (*)[HID])(smem + 8 * HID * 4);
    float* tab_s = (float*)smem;
    float* pos_s = (float*)(smem + (K_TAB + 4) * 4);

    const int t    = threadIdx.x;
    const int wave = t >> 6;
    const int lane = t & 63;
    const float dU  = (U1f - U0f) / (float)K_TAB;
    const float b3v = b3[0];

    // ---------------- Phase 1: build table ----------------
    for (int e0 = blockIdx.x * 8; e0 < K_TAB; e0 += gridDim.x * 8) {
        // h1 for 8 entries x 128 units = 1024 tasks
        for (int tau = t; tau < 8 * HID; tau += 256) {
            int ee = tau >> 7, n = tau & 127;
            float u    = U0f + (float)(e0 + ee) * dU;
            float d    = fast_exp2(u);
            float invc = fast_rcp(fmaxf(d, 0.01f));
            float inv2 = invc * invc;
            float z = fmaf(d, W1[n], fmaf(invc, W1[HID + n], fmaf(inv2, W1[2 * HID + n], b1[n])));
            h1s[ee][n] = fast_tanh(z);
        }
        __syncthreads();
        // layer 2: thread owns unit n for 4 entries; W2 row reads coalesced
        {
            int n = t & 127, eh = (t >> 7) * 4;
            float a0 = b2[n], a1 = a0, a2 = a0, a3 = a0;
#pragma unroll 8
            for (int k = 0; k < HID; ++k) {
                float w = W2[k * HID + n];
                a0 = fmaf(h1s[eh + 0][k], w, a0);
                a1 = fmaf(h1s[eh + 1][k], w, a1);
                a2 = fmaf(h1s[eh + 2][k], w, a2);
                a3 = fmaf(h1s[eh + 3][k], w, a3);
            }
            float w3n = W3[n];
            red[eh + 0][n] = fast_tanh(a0) * w3n;
            red[eh + 1][n] = fast_tanh(a1) * w3n;
            red[eh + 2][n] = fast_tanh(a2) * w3n;
            red[eh + 3][n] = fast_tanh(a3) * w3n;
        }
        __syncthreads();
        // reduce 128 -> 1 per entry; 4 waves x 2 entries
        for (int ee = wave; ee < 8; ee += 4) {
            float s = red[ee][lane] + red[ee][lane + 64];
#pragma unroll
            for (int off = 1; off < 64; off <<= 1) s += __shfl_xor(s, off);
            if (lane == 0) tabg[e0 + ee] = s + b3v;
        }
        __syncthreads();
    }
    // entry K_TAB (the lerp halo), block 0 only (uniform within the block)
    if (blockIdx.x == 0) {
        float d    = fast_exp2(U1f);
        float invc = fast_rcp(fmaxf(d, 0.01f));
        float inv2 = invc * invc;
        if (t < HID) {
            float z = fmaf(d, W1[t], fmaf(invc, W1[HID + t], fmaf(inv2, W1[2 * HID + t], b1[t])));
            h1s[0][t] = fast_tanh(z);
        }
        __syncthreads();
        if (t < HID) {
            float a = b2[t];
#pragma unroll 8
            for (int k = 0; k < HID; ++k) a = fmaf(h1s[0][k], W2[k * HID + t], a);
            red[0][t] = fast_tanh(a) * W3[t];
        }
        __syncthreads();
        if (wave == 0) {
            float s = red[0][lane] + red[0][lane + 64];
#pragma unroll
            for (int off = 1; off < 64; off <<= 1) s += __shfl_xor(s, off);
            if (lane == 0) tabg[K_TAB] = s + b3v;
        }
    }

    cg::this_grid().sync();

    // ---------------- Phase 2: forces ----------------
    const int b  = blockIdx.x / GPB;
    const int ig = blockIdx.x % GPB;

    for (int idx = t; idx <= K_TAB; idx += 256) tab_s[idx] = tabg[idx];
    {
        const float4* gp = (const float4*)(pos + b * NPTS * 3);
        float4* sp = (float4*)pos_s;
        for (int idx = t; idx < NPTS * 3 / 4; idx += 256) sp[idx] = gp[idx];
    }
    __syncthreads();

    const int   ia = ig * 8 + wave;        // first i of this wave
    const int   ib = ia + 4;               // second i
    const float pax = pos_s[ia * 3 + 0], pay = pos_s[ia * 3 + 1], paz = pos_s[ia * 3 + 2];
    const float pbx = pos_s[ib * 3 + 0], pby = pos_s[ib * 3 + 1], pbz = pos_s[ib * 3 + 2];
    const float S = (float)K_TAB / (U1f - U0f);

    float fax = 0.f, fay = 0.f, faz = 0.f;
    float fbx = 0.f, fby = 0.f, fbz = 0.f;
#pragma unroll 4
    for (int j = lane; j < NPTS; j += 64) {
        float qx = pos_s[j * 3 + 0], qy = pos_s[j * 3 + 1], qz = pos_s[j * 3 + 2];

        float dax = pax - qx, day = pay - qy, daz = paz - qz;
        float dbx = pbx - qx, dby = pby - qy, dbz = pbz - qz;
        float r2a = fmaf(dax, dax, fmaf(day, day, daz * daz));
        float r2b = fmaf(dbx, dbx, fmaf(dby, dby, dbz * dbz));

        float ta = fmaf(0.5f * fast_log2(r2a), S, -U0f * S);
        float tb = fmaf(0.5f * fast_log2(r2b), S, -U0f * S);
        float ka = fminf(fmaxf(floorf(ta), 0.0f), (float)(K_TAB - 1));
        float kb = fminf(fmaxf(floorf(tb), 0.0f), (float)(K_TAB - 1));
        float fra = fminf(fmaxf(ta - ka, 0.0f), 1.0f);
        float frb = fminf(fmaxf(tb - kb, 0.0f), 1.0f);
        int ia4 = (int)ka, ib4 = (int)kb;
        float va0 = tab_s[ia4], va1 = tab_s[ia4 + 1];
        float vb0 = tab_s[ib4], vb1 = tab_s[ib4 + 1];
        float maga = fmaf(va1 - va0, fra, va0);
        float magb = fmaf(vb1 - vb0, frb, vb0);

        float sa = maga * fminf(fast_rsq(r2a), 100.0f);   // mag/max(d,0.01); rsq(0)=inf->100
        float sb = magb * fminf(fast_rsq(r2b), 100.0f);
        fax = fmaf(sa, dax, fax); fay = fmaf(sa, day, fay); faz = fmaf(sa, daz, faz);
        fbx = fmaf(sb, dbx, fbx); fby = fmaf(sb, dby, fby); fbz = fmaf(sb, dbz, fbz);
    }
#pragma unroll
    for (int off = 1; off < 64; off <<= 1) {
        fax += __shfl_xor(fax, off); fay += __shfl_xor(fay, off); faz += __shfl_xor(faz, off);
        fbx += __shfl_xor(fbx, off); fby += __shfl_xor(fby, off); fbz += __shfl_xor(fbz, off);
    }
    if (lane == 0) {
        int oa = (b * NPTS + ia) * 3;
        int ob = (b * NPTS + ib) * 3;
        out[oa + 0] = fax; out[oa + 1] = fay; out[oa + 2] = faz;
        out[ob + 0] = fbx; out[ob + 1] = fby; out[ob + 2] = fbz;
    }
}

extern "C" void kernel_launch(void* const* d_in, const int* in_sizes, int n_in,
                              void* d_out, int out_size, void* d_ws, size_t ws_size,
                              hipStream_t stream) {
    const float* pos = (const float*)d_in[0];
    const float* W1  = (const float*)d_in[1];
    const float* b1  = (const float*)d_in[2];
    const float* W2  = (const float*)d_in[3];
    const float* b2  = (const float*)d_in[4];
    const float* W3  = (const float*)d_in[5];
    const float* b3  = (const float*)d_in[6];
    float* out  = (float*)d_out;
    float* tabg = (float*)d_ws;   // (K_TAB+1) floats

    int B = (in_sizes[0] / 3) / NPTS;
    dim3 grid(B * GPB), block(256);
    void* args[] = { (void*)&pos, (void*)&W1, (void*)&b1, (void*)&W2, (void*)&b2,
                     (void*)&W3, (void*)&b3, (void*)&tabg, (void*)&out };
    hipLaunchCooperativeKernel((const void*)discovery_fused, grid, block, args, 0, stream);
}

// Round 6
// 79.197 us; speedup vs baseline: 1.8340x; 1.8340x over previous
//
#include <hip/hip_runtime.h>

#define NPTS   1024
#define HID    128
#define K_TAB  2048
#define U0f    (-10.0f)
#define U1f    (4.0f)

__device__ __forceinline__ float fast_exp2(float x) {
#if __has_builtin(__builtin_amdgcn_exp2f)
    return __builtin_amdgcn_exp2f(x);
#else
    return exp2f(x);
#endif
}
__device__ __forceinline__ float fast_rcp(float x) {
#if __has_builtin(__builtin_amdgcn_rcpf)
    return __builtin_amdgcn_rcpf(x);
#else
    return 1.0f / x;
#endif
}
__device__ __forceinline__ float fast_log2(float x) {
#if __has_builtin(__builtin_amdgcn_logf)
    return __builtin_amdgcn_logf(x);
#else
    return __log2f(x);
#endif
}
__device__ __forceinline__ float fast_rsq(float x) {
#if __has_builtin(__builtin_amdgcn_rsqf)
    return __builtin_amdgcn_rsqf(x);
#else
    return rsqrtf(x);
#endif
}
// tanh(x) = 1 - 2/(e^{2x}+1). Saturates correctly at +-inf.
__device__ __forceinline__ float fast_tanh(float x) {
    float e = fast_exp2(2.8853900817779268f * x);
    return 1.0f - 2.0f * fast_rcp(e + 1.0f);
}

// ---------------------------------------------------------------------------
// Kernel 1: mag(d) table, value-only, K_TAB+1 entries uniform in u = log2(d),
// d in [2^-10, 2^4]. 257 blocks x 8 entries (block 256 produces the halo
// entry at index K_TAB; its other 7 slots clamp and are discarded).
// W2 read directly from global/L2, coalesced — no LDS staging.
// ---------------------------------------------------------------------------
__global__ __launch_bounds__(256) void build_table(const float* __restrict__ W1,
                                                   const float* __restrict__ b1,
                                                   const float* __restrict__ W2,
                                                   const float* __restrict__ b2,
                                                   const float* __restrict__ W3,
                                                   const float* __restrict__ b3,
                                                   float* __restrict__ tab)
{
    __shared__ float h1s[8][HID];
    __shared__ float red[8][HID];

    const int t = threadIdx.x, wave = t >> 6, lane = t & 63;
    const float dU  = (U1f - U0f) / (float)K_TAB;
    const float b3v = b3[0];
    const int   e0  = blockIdx.x * 8;

    // h1 for 8 entries x 128 units
    for (int tau = t; tau < 8 * HID; tau += 256) {
        int ee = tau >> 7, n = tau & 127;
        int e  = e0 + ee; if (e > K_TAB) e = K_TAB;   // halo block clamps
        float u    = U0f + (float)e * dU;
        float d    = fast_exp2(u);
        float invc = fast_rcp(fmaxf(d, 0.01f));
        float inv2 = invc * invc;
        float z = fmaf(d, W1[n], fmaf(invc, W1[HID + n], fmaf(inv2, W1[2 * HID + n], b1[n])));
        h1s[ee][n] = fast_tanh(z);
    }
    __syncthreads();
    // layer 2: thread owns unit n for 4 entries; W2 rows read coalesced from L2
    {
        int n = t & 127, eh = (t >> 7) * 4;
        float a0 = b2[n], a1 = a0, a2 = a0, a3 = a0;
#pragma unroll 8
        for (int k = 0; k < HID; ++k) {
            float w = W2[k * HID + n];
            a0 = fmaf(h1s[eh + 0][k], w, a0);
            a1 = fmaf(h1s[eh + 1][k], w, a1);
            a2 = fmaf(h1s[eh + 2][k], w, a2);
            a3 = fmaf(h1s[eh + 3][k], w, a3);
        }
        float w3n = W3[n];
        red[eh + 0][n] = fast_tanh(a0) * w3n;
        red[eh + 1][n] = fast_tanh(a1) * w3n;
        red[eh + 2][n] = fast_tanh(a2) * w3n;
        red[eh + 3][n] = fast_tanh(a3) * w3n;
    }
    __syncthreads();
    // reduce 128 -> 1 per entry; 4 waves x 2 entries
    for (int ee = wave; ee < 8; ee += 4) {
        float s = red[ee][lane] + red[ee][lane + 64];
#pragma unroll
        for (int off = 1; off < 64; off <<= 1) s += __shfl_xor(s, off);
        if (lane == 0 && e0 + ee <= K_TAB) tab[e0 + ee] = s + b3v;
    }
}

// ---------------------------------------------------------------------------
// Kernel 2: forces. 128 blocks per batch, 8 i's per block, one wave per 2 i's.
// Per pair: r^2, u = 0.5*log2(r^2) (no sqrt), table lerp, f += mag*diff*rsq.
// Self-pair contributes 0 (diff = 0). Each output written exactly once.
// ---------------------------------------------------------------------------
__global__ __launch_bounds__(256) void forces_kernel(const float* __restrict__ pos,
                                                     const float* __restrict__ tab,
                                                     float* __restrict__ out)
{
    __shared__ float tab_s[K_TAB + 4];   // 8.2 KB
    __shared__ float pos_s[NPTS * 3];    // 12 KB

    const int t = threadIdx.x, wave = t >> 6, lane = t & 63;
    const int b  = blockIdx.x >> 7;      // 128 blocks per batch
    const int ig = blockIdx.x & 127;

    for (int idx = t; idx <= K_TAB; idx += 256) tab_s[idx] = tab[idx];
    {
        const float4* gp = (const float4*)(pos + b * NPTS * 3);
        float4* sp = (float4*)pos_s;
        for (int idx = t; idx < NPTS * 3 / 4; idx += 256) sp[idx] = gp[idx];
    }
    __syncthreads();

    const int   ia = ig * 8 + wave;      // first i of this wave
    const int   ib = ia + 4;             // second i
    const float pax = pos_s[ia * 3 + 0], pay = pos_s[ia * 3 + 1], paz = pos_s[ia * 3 + 2];
    const float pbx = pos_s[ib * 3 + 0], pby = pos_s[ib * 3 + 1], pbz = pos_s[ib * 3 + 2];
    const float S = (float)K_TAB / (U1f - U0f);

    float fax = 0.f, fay = 0.f, faz = 0.f;
    float fbx = 0.f, fby = 0.f, fbz = 0.f;
#pragma unroll 4
    for (int j = lane; j < NPTS; j += 64) {
        float qx = pos_s[j * 3 + 0], qy = pos_s[j * 3 + 1], qz = pos_s[j * 3 + 2];

        float dax = pax - qx, day = pay - qy, daz = paz - qz;
        float dbx = pbx - qx, dby = pby - qy, dbz = pbz - qz;
        float r2a = fmaf(dax, dax, fmaf(day, day, daz * daz));
        float r2b = fmaf(dbx, dbx, fmaf(dby, dby, dbz * dbz));

        float ta = fmaf(0.5f * fast_log2(r2a), S, -U0f * S);
        float tb = fmaf(0.5f * fast_log2(r2b), S, -U0f * S);
        float ka = fminf(fmaxf(floorf(ta), 0.0f), (float)(K_TAB - 1));
        float kb = fminf(fmaxf(floorf(tb), 0.0f), (float)(K_TAB - 1));
        float fra = fminf(fmaxf(ta - ka, 0.0f), 1.0f);
        float frb = fminf(fmaxf(tb - kb, 0.0f), 1.0f);
        int ka_i = (int)ka, kb_i = (int)kb;
        float va0 = tab_s[ka_i], va1 = tab_s[ka_i + 1];
        float vb0 = tab_s[kb_i], vb1 = tab_s[kb_i + 1];
        float maga = fmaf(va1 - va0, fra, va0);
        float magb = fmaf(vb1 - vb0, frb, vb0);

        float sa = maga * fminf(fast_rsq(r2a), 100.0f);   // mag/max(d,0.01); rsq(0)=inf->100
        float sb = magb * fminf(fast_rsq(r2b), 100.0f);
        fax = fmaf(sa, dax, fax); fay = fmaf(sa, day, fay); faz = fmaf(sa, daz, faz);
        fbx = fmaf(sb, dbx, fbx); fby = fmaf(sb, dby, fby); fbz = fmaf(sb, dbz, fbz);
    }
#pragma unroll
    for (int off = 1; off < 64; off <<= 1) {
        fax += __shfl_xor(fax, off); fay += __shfl_xor(fay, off); faz += __shfl_xor(faz, off);
        fbx += __shfl_xor(fbx, off); fby += __shfl_xor(fby, off); fbz += __shfl_xor(fbz, off);
    }
    if (lane == 0) {
        int oa = (b * NPTS + ia) * 3;
        int ob = (b * NPTS + ib) * 3;
        out[oa + 0] = fax; out[oa + 1] = fay; out[oa + 2] = faz;
        out[ob + 0] = fbx; out[ob + 1] = fby; out[ob + 2] = fbz;
    }
}

extern "C" void kernel_launch(void* const* d_in, const int* in_sizes, int n_in,
                              void* d_out, int out_size, void* d_ws, size_t ws_size,
                              hipStream_t stream) {
    const float* pos = (const float*)d_in[0];
    const float* W1  = (const float*)d_in[1];
    const float* b1  = (const float*)d_in[2];
    const float* W2  = (const float*)d_in[3];
    const float* b2  = (const float*)d_in[4];
    const float* W3  = (const float*)d_in[5];
    const float* b3  = (const float*)d_in[6];
    float* out  = (float*)d_out;
    float* tab  = (float*)d_ws;   // (K_TAB+1) floats

    int B = (in_sizes[0] / 3) / NPTS;
    build_table<<<K_TAB / 8 + 1, 256, 0, stream>>>(W1, b1, W2, b2, W3, b3, tab);
    forces_kernel<<<B * 128, 256, 0, stream>>>(pos, tab, out);
}